// Round 1
// baseline (162.921 us; speedup 1.0000x reference)
//
#include <hip/hip_runtime.h>

#define GS 7
#define NB 2
#define NC 20
#define CC 30           // 5*NB + NC
#define CELLS_PER_BLOCK 256

__global__ void zero_out_kernel(float* out) {
    if (threadIdx.x < 3) out[threadIdx.x] = 0.0f;
}

__global__ __launch_bounds__(256) void yolo_loss_kernel(
        const float* __restrict__ in,
        const float* __restrict__ tg,
        float* __restrict__ out,
        int ncells, float inv_bs) {
    __shared__ float s_in[CELLS_PER_BLOCK * CC];
    __shared__ float s_tg[CELLS_PER_BLOCK * CC];
    __shared__ float s_red[4][3];

    const int tid  = threadIdx.x;
    const int base = blockIdx.x * CELLS_PER_BLOCK;
    int n = ncells - base;
    if (n > CELLS_PER_BLOCK) n = CELLS_PER_BLOCK;

    // ---- Stage: global -> LDS, fully coalesced ----
    if (n == CELLS_PER_BLOCK) {
        // 256 cells * 30 floats = 7680 floats = 1920 float4; block base is 16B-aligned.
        const float4* gin = (const float4*)(in + (size_t)base * CC);
        const float4* gtg = (const float4*)(tg + (size_t)base * CC);
        float4* lin = (float4*)s_in;
        float4* ltg = (float4*)s_tg;
        #pragma unroll
        for (int k = 0; k < 8; ++k) {
            int idx = tid + k * 256;
            if (idx < 1920) {
                lin[idx] = gin[idx];
                ltg[idx] = gtg[idx];
            }
        }
    } else {
        int lim = n * CC;
        for (int k = tid; k < lim; k += 256) {
            s_in[k] = in[(size_t)base * CC + k];
            s_tg[k] = tg[(size_t)base * CC + k];
        }
    }
    __syncthreads();

    // ---- Per-cell compute ----
    float a_boxes = 0.0f, a_conf = 0.0f, a_class = 0.0f;
    if (tid < n) {
        const float* ip = s_in + tid * CC;   // stride 30 -> 2-way LDS bank alias (free)
        const float* tp = s_tg + tid * CC;

        const float conf_t = tp[4];
        const float coord  = (conf_t > 0.0f)  ? 1.0f : 0.0f;
        const float noobj  = (conf_t == 0.0f) ? 1.0f : 0.0f;

        // no-object confidence loss (both predicted boxes)
        const float d0 = ip[4] - tp[4];
        const float d1 = ip[9] - tp[9];
        const float l_noobj = noobj * (d0 * d0 + d1 * d1);

        // target box (box 0 of targets)
        const float bt0 = tp[0], bt1 = tp[1], bt2 = tp[2], bt3 = tp[3];
        const float ttx = bt0 / 7.0f, tty = bt1 / 7.0f;
        const float txmin = ttx - 0.5f * bt2, tymin = tty - 0.5f * bt3;
        const float txmax = ttx + 0.5f * bt2, tymax = tty + 0.5f * bt3;
        const float tarea = (txmax - txmin) * (tymax - tymin);

        float iou[2];
        #pragma unroll
        for (int b = 0; b < 2; ++b) {
            const float x = ip[b * 5 + 0], y = ip[b * 5 + 1];
            const float w = ip[b * 5 + 2], h = ip[b * 5 + 3];
            const float px = x / 7.0f, py = y / 7.0f;
            const float pxmin = px - 0.5f * w, pymin = py - 0.5f * h;
            const float pxmax = px + 0.5f * w, pymax = py + 0.5f * h;
            const float ltx = fmaxf(pxmin, txmin), lty = fmaxf(pymin, tymin);
            const float rbx = fminf(pxmax, txmax), rby = fminf(pymax, tymax);
            const float wx = fmaxf(rbx - ltx, 0.0f), wy = fmaxf(rby - lty, 0.0f);
            const float inter = wx * wy;
            const float parea = (pxmax - pxmin) * (pymax - pymin);
            iou[b] = inter / (parea + tarea - inter);
        }
        // jnp.argmax picks the FIRST max on ties -> strict > for box 1
        const int   sel     = (iou[1] > iou[0]) ? 1 : 0;
        const float max_iou = fmaxf(iou[0], iou[1]);

        const float rp0 = ip[sel * 5 + 0], rp1 = ip[sel * 5 + 1];
        const float rp2 = ip[sel * 5 + 2], rp3 = ip[sel * 5 + 3];
        const float rp4 = ip[sel * 5 + 4];

        const float dx = rp0 - bt0, dy = rp1 - bt1;
        const float l_xy = dx * dx + dy * dy;
        const float sw = sqrtf(rp2) - sqrtf(bt2);
        const float sh = sqrtf(rp3) - sqrtf(bt3);
        const float l_wh = sw * sw + sh * sh;
        const float dob = rp4 - max_iou;
        const float l_obj = dob * dob;

        float l_cls = 0.0f;
        #pragma unroll
        for (int k = 10; k < 30; ++k) {
            const float d = ip[k] - tp[k];
            l_cls += d * d;
        }

        a_boxes = coord * (l_xy + l_wh);
        a_conf  = coord * l_obj + 0.5f * l_noobj;
        a_class = coord * l_cls;
    }

    // ---- Reduce: wave-64 shuffle, then cross-wave via LDS ----
    #pragma unroll
    for (int off = 32; off > 0; off >>= 1) {
        a_boxes += __shfl_down(a_boxes, off, 64);
        a_conf  += __shfl_down(a_conf,  off, 64);
        a_class += __shfl_down(a_class, off, 64);
    }
    const int wave = tid >> 6;
    if ((tid & 63) == 0) {
        s_red[wave][0] = a_boxes;
        s_red[wave][1] = a_conf;
        s_red[wave][2] = a_class;
    }
    __syncthreads();
    if (tid == 0) {
        const float b = s_red[0][0] + s_red[1][0] + s_red[2][0] + s_red[3][0];
        const float c = s_red[0][1] + s_red[1][1] + s_red[2][1] + s_red[3][1];
        const float k = s_red[0][2] + s_red[1][2] + s_red[2][2] + s_red[3][2];
        atomicAdd(&out[0], 0.5f * b * inv_bs);   // LAMBDA_COORD*(xy+wh)/bs
        atomicAdd(&out[1], c * inv_bs);          // (obj + 0.5*noobj)/bs
        atomicAdd(&out[2], k * inv_bs);          // class/bs
    }
}

extern "C" void kernel_launch(void* const* d_in, const int* in_sizes, int n_in,
                              void* d_out, int out_size, void* d_ws, size_t ws_size,
                              hipStream_t stream) {
    const float* in = (const float*)d_in[0];
    const float* tg = (const float*)d_in[1];
    float* out = (float*)d_out;

    const int B = in_sizes[0] / (GS * GS * CC);
    const int ncells = B * GS * GS;
    const float inv_bs = 1.0f / (float)B;
    const int nblocks = (ncells + CELLS_PER_BLOCK - 1) / CELLS_PER_BLOCK;

    zero_out_kernel<<<1, 64, 0, stream>>>(out);
    yolo_loss_kernel<<<nblocks, 256, 0, stream>>>(in, tg, out, ncells, inv_bs);
}

// Round 3
// 123.375 us; speedup vs baseline: 1.3205x; 1.3205x over previous
//
#include <hip/hip_runtime.h>

#define GS 7
#define CC 30           // 5*NB + NC

// ---------------- main kernel: per-cell losses, block partials to ws ----------------
__global__ __launch_bounds__(256) void yolo_main(
        const float* __restrict__ in,
        const float* __restrict__ tg,
        float* __restrict__ ws,
        int ncells, int pstride) {
    const int tid      = blockIdx.x * 256 + threadIdx.x;
    const int nthreads = gridDim.x * 256;

    float a_boxes = 0.0f, a_conf = 0.0f, a_class = 0.0f;

    for (int cell = tid; cell < ncells; cell += nthreads) {
        // cell base = cell*120 bytes -> 8B aligned, float2 loads are legal.
        const float2* ip = (const float2*)(in + (size_t)cell * CC);
        const float2* tp = (const float2*)(tg + (size_t)cell * CC);

        // inputs: all 15 float2 (30 floats)
        const float2 i0 = ip[0],  i1 = ip[1],  i2 = ip[2],  i3 = ip[3],  i4 = ip[4];
        const float2 i5 = ip[5],  i6 = ip[6],  i7 = ip[7],  i8 = ip[8],  i9 = ip[9];
        const float2 i10 = ip[10], i11 = ip[11], i12 = ip[12], i13 = ip[13], i14 = ip[14];
        // targets: box0 (0..3), conf (4), conf2 (9), classes (10..29) -> 14 float2
        const float2 t0 = tp[0],  t1 = tp[1],  t2 = tp[2],  t4 = tp[4];
        const float2 t5 = tp[5],  t6 = tp[6],  t7 = tp[7],  t8 = tp[8],  t9 = tp[9];
        const float2 t10 = tp[10], t11 = tp[11], t12 = tp[12], t13 = tp[13], t14 = tp[14];

        const float conf_t = t2.x;                      // tg[4]
        const float coord  = (conf_t > 0.0f)  ? 1.0f : 0.0f;
        const float noobj  = (conf_t == 0.0f) ? 1.0f : 0.0f;

        // no-object confidence loss: both predicted boxes vs tg[4], tg[9]
        const float d0 = i2.x - conf_t;                 // in[4] - tg[4]
        const float d1 = i4.y - t4.y;                   // in[9] - tg[9]
        const float l_noobj = noobj * (d0 * d0 + d1 * d1);   // mask applied HERE (R2 bug fix)

        // target box corners
        const float bt0 = t0.x, bt1 = t0.y, bt2 = t1.x, bt3 = t1.y;
        const float ttx = bt0 / 7.0f, tty = bt1 / 7.0f;
        const float txmin = ttx - 0.5f * bt2, tymin = tty - 0.5f * bt3;
        const float txmax = ttx + 0.5f * bt2, tymax = tty + 0.5f * bt3;
        const float tarea = (txmax - txmin) * (tymax - tymin);

        // predicted boxes
        const float px0 = i0.x, py0 = i0.y, pw0 = i1.x, ph0 = i1.y, pc0 = i2.x;
        const float px1 = i2.y, py1 = i3.x, pw1 = i3.y, ph1 = i4.x, pc1 = i4.y;

        float iou[2];
        {
            const float cx = px0 / 7.0f, cy = py0 / 7.0f;
            const float xmin = cx - 0.5f * pw0, ymin = cy - 0.5f * ph0;
            const float xmax = cx + 0.5f * pw0, ymax = cy + 0.5f * ph0;
            const float wx = fmaxf(fminf(xmax, txmax) - fmaxf(xmin, txmin), 0.0f);
            const float wy = fmaxf(fminf(ymax, tymax) - fmaxf(ymin, tymin), 0.0f);
            const float inter = wx * wy;
            const float parea = (xmax - xmin) * (ymax - ymin);
            iou[0] = inter / (parea + tarea - inter);
        }
        {
            const float cx = px1 / 7.0f, cy = py1 / 7.0f;
            const float xmin = cx - 0.5f * pw1, ymin = cy - 0.5f * ph1;
            const float xmax = cx + 0.5f * pw1, ymax = cy + 0.5f * ph1;
            const float wx = fmaxf(fminf(xmax, txmax) - fmaxf(xmin, txmin), 0.0f);
            const float wy = fmaxf(fminf(ymax, tymax) - fmaxf(ymin, tymin), 0.0f);
            const float inter = wx * wy;
            const float parea = (xmax - xmin) * (ymax - ymin);
            iou[1] = inter / (parea + tarea - inter);
        }
        // jnp.argmax picks first max on ties -> strict > for box 1
        const bool  sel1    = iou[1] > iou[0];
        const float max_iou = fmaxf(iou[0], iou[1]);

        const float rp0 = sel1 ? px1 : px0;
        const float rp1 = sel1 ? py1 : py0;
        const float rp2 = sel1 ? pw1 : pw0;
        const float rp3 = sel1 ? ph1 : ph0;
        const float rp4 = sel1 ? pc1 : pc0;

        const float dx = rp0 - bt0, dy = rp1 - bt1;
        const float sw = sqrtf(rp2) - sqrtf(bt2);
        const float sh = sqrtf(rp3) - sqrtf(bt3);
        const float dob = rp4 - max_iou;
        const float l_box = dx * dx + dy * dy + sw * sw + sh * sh;
        const float l_obj = dob * dob;

        // class loss: channels 10..29
        float l_cls = 0.0f;
        {
            float gx, gy;
            gx = i5.x  - t5.x;  gy = i5.y  - t5.y;  l_cls += gx * gx + gy * gy;
            gx = i6.x  - t6.x;  gy = i6.y  - t6.y;  l_cls += gx * gx + gy * gy;
            gx = i7.x  - t7.x;  gy = i7.y  - t7.y;  l_cls += gx * gx + gy * gy;
            gx = i8.x  - t8.x;  gy = i8.y  - t8.y;  l_cls += gx * gx + gy * gy;
            gx = i9.x  - t9.x;  gy = i9.y  - t9.y;  l_cls += gx * gx + gy * gy;
            gx = i10.x - t10.x; gy = i10.y - t10.y; l_cls += gx * gx + gy * gy;
            gx = i11.x - t11.x; gy = i11.y - t11.y; l_cls += gx * gx + gy * gy;
            gx = i12.x - t12.x; gy = i12.y - t12.y; l_cls += gx * gx + gy * gy;
            gx = i13.x - t13.x; gy = i13.y - t13.y; l_cls += gx * gx + gy * gy;
            gx = i14.x - t14.x; gy = i14.y - t14.y; l_cls += gx * gx + gy * gy;
        }

        a_boxes += coord * l_box;
        a_conf  += coord * l_obj + 0.5f * l_noobj;
        a_class += coord * l_cls;
    }

    // wave-64 shuffle reduce
    #pragma unroll
    for (int off = 32; off > 0; off >>= 1) {
        a_boxes += __shfl_down(a_boxes, off, 64);
        a_conf  += __shfl_down(a_conf,  off, 64);
        a_class += __shfl_down(a_class, off, 64);
    }
    __shared__ float s_red[4][3];
    const int wave = threadIdx.x >> 6;
    if ((threadIdx.x & 63) == 0) {
        s_red[wave][0] = a_boxes;
        s_red[wave][1] = a_conf;
        s_red[wave][2] = a_class;
    }
    __syncthreads();
    if (threadIdx.x == 0) {
        const float b = s_red[0][0] + s_red[1][0] + s_red[2][0] + s_red[3][0];
        const float c = s_red[0][1] + s_red[1][1] + s_red[2][1] + s_red[3][1];
        const float k = s_red[0][2] + s_red[1][2] + s_red[2][2] + s_red[3][2];
        // non-atomic block partials -> no same-address contention
        ws[blockIdx.x]               = b;
        ws[blockIdx.x + pstride]     = c;
        ws[blockIdx.x + 2 * pstride] = k;
    }
}

// ---------------- finalize: sum block partials, scale, write out ----------------
__global__ __launch_bounds__(256) void yolo_finalize(
        const float* __restrict__ ws, float* __restrict__ out,
        int nblocks, int pstride, float inv_bs) {
    float b = 0.0f, c = 0.0f, k = 0.0f;
    for (int i = threadIdx.x; i < nblocks; i += 256) {
        b += ws[i];
        c += ws[i + pstride];
        k += ws[i + 2 * pstride];
    }
    #pragma unroll
    for (int off = 32; off > 0; off >>= 1) {
        b += __shfl_down(b, off, 64);
        c += __shfl_down(c, off, 64);
        k += __shfl_down(k, off, 64);
    }
    __shared__ float s_red[4][3];
    const int wave = threadIdx.x >> 6;
    if ((threadIdx.x & 63) == 0) {
        s_red[wave][0] = b;
        s_red[wave][1] = c;
        s_red[wave][2] = k;
    }
    __syncthreads();
    if (threadIdx.x == 0) {
        const float tb = s_red[0][0] + s_red[1][0] + s_red[2][0] + s_red[3][0];
        const float tc = s_red[0][1] + s_red[1][1] + s_red[2][1] + s_red[3][1];
        const float tk = s_red[0][2] + s_red[1][2] + s_red[2][2] + s_red[3][2];
        out[0] = 0.5f * tb * inv_bs;   // LAMBDA_COORD*(xy+wh)/bs
        out[1] = tc * inv_bs;          // (obj + 0.5*noobj)/bs
        out[2] = tk * inv_bs;          // class/bs
    }
}

extern "C" void kernel_launch(void* const* d_in, const int* in_sizes, int n_in,
                              void* d_out, int out_size, void* d_ws, size_t ws_size,
                              hipStream_t stream) {
    const float* in = (const float*)d_in[0];
    const float* tg = (const float*)d_in[1];
    float* out = (float*)d_out;
    float* ws  = (float*)d_ws;

    const int ncells = in_sizes[0] / CC;          // B * 49
    const int B = ncells / (GS * GS);
    const float inv_bs = 1.0f / (float)B;

    // 2 cells per thread: 784 blocks at B=8192 (exactly 2 iterations, no tail)
    const int nblocks = (ncells + 511) / 512;
    const int pstride = nblocks;

    yolo_main<<<nblocks, 256, 0, stream>>>(in, tg, ws, ncells, pstride);
    yolo_finalize<<<1, 256, 0, stream>>>(ws, out, nblocks, pstride, inv_bs);
}